// Round 5
// baseline (198.347 us; speedup 1.0000x reference)
//
#include <hip/hip_runtime.h>

// Levenshtein edit distance, ref (512,B) x hyp (512,B), B=1024, unit costs.
// Anti-diagonal wavefront. Round-5 change: each problem is split across TWO
// waves of a 128-thread block (4 cells/lane) -> 2048 waves = 2 waves/SIMD.
// Evidence (r1-r4): at 1 wave/SIMD the schedule is latency-bound (~335
// cyc/step, VALU issuing only ~36%); co-resident waves are the native fix.
//
// Values relative to diagonal d (v' = v - d), verified absmax=0 since r1:
//   AN[k] = min(A1[k-1], A1[k], A2[k-1] - 1 - (ref==hyp))
// i=0 boundary: inject 0 (DPP old operand). j=0 boundary: LARGE init.
// Cross-wave boundary (cell 255 -> 256): wave0 lane63 publishes
// {AN[3], ht[3]} each step into a 3-slot LDS ring (slot = rotation phase,
// compile-time constant; overwritten only 3 steps after its read).
// Wave1's A2-boundary = previous step's received value (r2 algebra), so
// only 8 bytes cross per step. One __syncthreads per step; both wave paths
// execute identical barrier counts.

#define RLEN 512
#define HLEN 512
#define BATCH 1024
#define LARGE (1 << 20)

// lane L gets src from lane L-1; lane 0 gets `old` (gfx9 DPP WAVE_SHR1,
// bound_ctrl=false). HW-verified rounds 3-4.
__device__ __forceinline__ int shfl_up1(int old, int src) {
  return __builtin_amdgcn_update_dpp(old, src, 0x138, 0xF, 0xF, false);
}

__global__ void __launch_bounds__(128)
edit_distance_kernel(const int* __restrict__ ref,
                     const int* __restrict__ hyp,
                     float* __restrict__ out) {
  const int b = blockIdx.x;              // one block per batch element
  const int lane = threadIdx.x & 63;
  const int wave = threadIdx.x >> 6;     // 0: cells 0..255, 1: cells 256..511

  __shared__ int2 slot[3];               // {boundary value, boundary token}
  if (threadIdx.x < 3) slot[threadIdx.x] = make_int2(LARGE, -1);

  // Static ref tokens: cell c = wave*256 + lane*4 + k (matrix row i = c+1).
  int rt[4];
#pragma unroll
  for (int k = 0; k < 4; ++k)
    rt[k] = ref[(wave * 256 + lane * 4 + k) * BATCH + b];

  // Rotating diagonal buffers (relative domain) + hyp token queue.
  int A[4], Bv[4], Cv[4], ht[4];
#pragma unroll
  for (int k = 0; k < 4; ++k) { A[k] = LARGE; Bv[k] = LARGE; ht[k] = -1; }

  __syncthreads();  // slot init visible before first read

  if (wave == 0) {
    if (lane == 0) { Bv[0] = 0; ht[0] = hyp[b]; }  // D[1][0] rel; hyp0[0]
    int d = 2;
    int t0 = hyp[min(d - 1, HLEN - 1) * BATCH + b];
    int t1 = hyp[min(d + 0, HLEN - 1) * BATCH + b];
    int t2 = hyp[min(d + 1, HLEN - 1) * BATCH + b];

#define STEP0(A2, A1, AN, tok, WS)                                    \
    {                                                                 \
      int a1m = shfl_up1(0, A1[3]);                                   \
      int a2m = shfl_up1(0, A2[3]);                                   \
      int uph = shfl_up1(tok, ht[3]);                                 \
      _Pragma("unroll")                                               \
      for (int k = 3; k >= 1; --k) {                                  \
        int cand = A2[k - 1] - 1 - (rt[k] == ht[k]);                  \
        AN[k] = min(min(A1[k - 1], A1[k]), cand);                     \
      }                                                               \
      AN[0] = min(min(a1m, A1[0]), a2m - 1 - (rt[0] == ht[0]));       \
      if (lane == 63) slot[WS] = make_int2(AN[3], ht[3]);             \
      ht[3] = ht[2]; ht[2] = ht[1]; ht[1] = ht[0]; ht[0] = uph;       \
      __syncthreads();                                                \
    }

    for (int it = 0; it < 341; ++it) {   // 1023 steps, d = 2..1024
      int n0 = hyp[min(d + 2, HLEN - 1) * BATCH + b];
      int n1 = hyp[min(d + 3, HLEN - 1) * BATCH + b];
      int n2 = hyp[min(d + 4, HLEN - 1) * BATCH + b];
      STEP0(A, Bv, Cv, t0, 0);
      STEP0(Bv, Cv, A, t1, 1);
      STEP0(Cv, A, Bv, t2, 2);
      d += 3; t0 = n0; t1 = n1; t2 = n2;
    }
  } else {
    int prevRv = LARGE;  // A2-boundary = value received one step earlier

#define STEP1(A2, A1, AN, RS)                                         \
    {                                                                 \
      int2 rb = slot[RS]; /* issued early; consumed ~18 instr later */\
      _Pragma("unroll")                                               \
      for (int k = 3; k >= 1; --k) {                                  \
        int cand = A2[k - 1] - 1 - (rt[k] == ht[k]);                  \
        AN[k] = min(min(A1[k - 1], A1[k]), cand);                     \
      }                                                               \
      int a1m = shfl_up1(rb.x, A1[3]);                                \
      int a2m = shfl_up1(prevRv, A2[3]);                              \
      int uph = shfl_up1(rb.y, ht[3]);                                \
      AN[0] = min(min(a1m, A1[0]), a2m - 1 - (rt[0] == ht[0]));       \
      ht[3] = ht[2]; ht[2] = ht[1]; ht[1] = ht[0]; ht[0] = uph;       \
      prevRv = rb.x;                                                  \
      __syncthreads();                                                \
    }

    for (int it = 0; it < 341; ++it) {
      STEP1(A, Bv, Cv, 2);   // reads what phase-2 of prev iter wrote
      STEP1(Bv, Cv, A, 0);
      STEP1(Cv, A, Bv, 1);
    }

    // Answer: cell 511 = wave1 lane63 k=3, diag 1024 in Bv; v = v' + 1024.
    if (lane == 63) out[b] = (float)(Bv[3] + (RLEN + HLEN));
  }
}

extern "C" void kernel_launch(void* const* d_in, const int* in_sizes, int n_in,
                              void* d_out, int out_size, void* d_ws, size_t ws_size,
                              hipStream_t stream) {
  const int* ref = (const int*)d_in[0];
  const int* hyp = (const int*)d_in[1];
  float* out = (float*)d_out;
  edit_distance_kernel<<<BATCH, 128, 0, stream>>>(ref, hyp, out);
}

// Round 6
// 157.408 us; speedup vs baseline: 1.2601x; 1.2601x over previous
//
#include <hip/hip_runtime.h>

// Levenshtein edit distance, ref (512,B) x hyp (512,B), B=1024, unit costs.
// Anti-diagonal wavefront, one 64-lane wave per batch element, 8 cells/lane.
// Values relative to diagonal d (v' = v - d), verified absmax=0 (r1,r3,r4):
//   AN[k] = min(A1[k-1], A1[k], A2[k-1] - 1 - (ref==hyp))
// i=0 boundary: inject 0 via DPP old operand. j=0 boundary: LARGE init.
//
// Round-6 change: wall/step was ~340 cyc across r1/r3/r4/r5 regardless of
// shuffle type, VALU count, or wave split -> the invariant critical path is
// the in-loop strided hyp global loads (4KB lane stride, 6x over-fetch in
// FETCH_SIZE, HBM-miss latency ~900 cyc ~= the 1-iter prefetch distance).
// Fix: stage the hyp column into LDS once (2KB), in-loop token prefetch is
// a uniform-address broadcast ds_read issued one full iteration ahead.

#define RLEN 512
#define HLEN 512
#define BATCH 1024
#define LARGE (1 << 20)

// lane L gets src from lane L-1; lane 0 gets `old` (gfx9 DPP WAVE_SHR1,
// bound_ctrl=false). HW-verified rounds 3-5.
__device__ __forceinline__ int shfl_up1(int old, int src) {
  return __builtin_amdgcn_update_dpp(old, src, 0x138, 0xF, 0xF, false);
}

// A2 = diag d-2 (rel), A1 = diag d-1 (rel), AN = output diag d (rel).
// Shifts the hyp-token queue, injecting tok_inject at lane 0 cell 0.
#define STEP(A2, A1, AN, tok_inject)                                  \
  {                                                                   \
    int a1m = shfl_up1(0, A1[7]);        /* A1'[i-1] for k==0 */      \
    int a2m = shfl_up1(0, A2[7]);        /* A2'[i-1] for k==0 */      \
    int uph = shfl_up1(tok_inject, ht[7]);                            \
    _Pragma("unroll")                                                 \
    for (int k = 7; k >= 1; --k) {                                    \
      int cand = A2[k - 1] - 1 - (rt[k] == ht[k]);                    \
      AN[k] = min(min(A1[k - 1], A1[k]), cand);                       \
    }                                                                 \
    AN[0] = min(min(a1m, A1[0]), a2m - 1 - (rt[0] == ht[0]));         \
    _Pragma("unroll")                                                 \
    for (int k = 7; k >= 1; --k) ht[k] = ht[k - 1];                   \
    ht[0] = uph;                                                      \
  }

__global__ void __launch_bounds__(64)
edit_distance_kernel(const int* __restrict__ ref,
                     const int* __restrict__ hyp,
                     float* __restrict__ out) {
  const int b = blockIdx.x;        // one wave (block of 64) per batch element
  const int lane = threadIdx.x;    // 0..63

  // Stage this problem's hyp column into LDS (one-time, outside the loop).
  __shared__ int hyp_s[HLEN];
#pragma unroll
  for (int c = 0; c < HLEN / 64; ++c)
    hyp_s[c * 64 + lane] = hyp[(c * 64 + lane) * BATCH + b];

  // Static ref tokens for this wave's cells c = lane*8+k  (i = c+1).
  int rt[8];
#pragma unroll
  for (int k = 0; k < 8; ++k)
    rt[k] = ref[(lane * 8 + k) * BATCH + b];

  __syncthreads();  // hyp_s visible

  // Three rotating diagonal buffers (relative domain).
  int A[8], Bv[8], Cv[8];
#pragma unroll
  for (int k = 0; k < 8; ++k) { A[k] = LARGE; Bv[k] = LARGE; }
  if (lane == 0) Bv[0] = 0;  // D[1][0]=1, rel diag d=1 -> 0

  // Hyp token queue: ht[k] = token for cell c at current step d = hyp0[d-c-2].
  int ht[8];
#pragma unroll
  for (int k = 0; k < 8; ++k) ht[k] = -1;
  if (lane == 0) ht[0] = hyp_s[0];  // hyp0[0], consumed by cell 0 at d=2

  // Injection tokens from LDS (broadcast reads): step d injects hyp0[d-1].
  int d = 2;
  int t0 = hyp_s[min(d - 1, HLEN - 1)];
  int t1 = hyp_s[min(d + 0, HLEN - 1)];
  int t2 = hyp_s[min(d + 1, HLEN - 1)];

  // 1023 diagonal steps (d = 2..1024), 3 per iteration, 341 iterations.
  for (int it = 0; it < 341; ++it) {
    int n0 = hyp_s[min(d + 2, HLEN - 1)];   // prefetch next iter's tokens:
    int n1 = hyp_s[min(d + 3, HLEN - 1)];   // ds_read ~120 cyc, consumed
    int n2 = hyp_s[min(d + 4, HLEN - 1)];   // one full iteration later
    STEP(A, Bv, Cv, t0);   // diag d
    STEP(Bv, Cv, A, t1);   // diag d+1
    STEP(Cv, A, Bv, t2);   // diag d+2
    d += 3;
    t0 = n0; t1 = n1; t2 = n2;
  }

  // Answer: D[512][512] on diag 1024 = Bv (last write), cell 511 = lane 63 k=7.
  if (lane == 63) out[b] = (float)(Bv[7] + (RLEN + HLEN));
}

extern "C" void kernel_launch(void* const* d_in, const int* in_sizes, int n_in,
                              void* d_out, int out_size, void* d_ws, size_t ws_size,
                              hipStream_t stream) {
  const int* ref = (const int*)d_in[0];
  const int* hyp = (const int*)d_in[1];
  float* out = (float*)d_out;
  edit_distance_kernel<<<BATCH, 64, 0, stream>>>(ref, hyp, out);
}